// Round 12
// baseline (25.766 us; speedup 1.0000x reference)
//
#include <hip/hip_runtime.h>

#define NF 17
#define NN 23
#define ED 16
#define BLK 1024
#define RPP 256      // rows per pass = BLK/4
#define RPB 512      // rows per block (2 passes); grid*RPB == nrows exactly
#define SROWS 862    // packed rows of the 14 small-vocab fields
#define SSTR 20      // padded floats per LDS row (80 B)

typedef int   int4u    __attribute__((ext_vector_type(4), aligned(4)));
typedef float float4u  __attribute__((ext_vector_type(4), aligned(4)));
typedef float float2u  __attribute__((ext_vector_type(2), aligned(4)));
typedef float float2v  __attribute__((ext_vector_type(2)));

// broadcast int k of the row from owner lane (k>>2) slot (k&3) to the 4-lane
// group. BitMode ds_swizzle: offset = (xor<<10)|(or<<5)|and; and=0x1C keeps
// group bits, or = k>>2 selects source lane.
#define SWZ(slotval, j) __builtin_amdgcn_ds_swizzle((slotval), ((j) << 5) | 0x1C)

// packed accumulate: 2x v_pk_add_f32 + 2x v_pk_fma_f32 per field
__device__ __forceinline__ void acc4(const float4 v, float2v& sa, float2v& sb,
                                     float2v& sq2) {
    const float2v lo = {v.x, v.y};
    const float2v hi = {v.z, v.w};
    sa += lo;
    sb += hi;
    sq2 += lo * lo;
    sq2 += hi * hi;
}

__global__ __launch_bounds__(BLK, 8) void ffm_fwd_kernel(
    const int* __restrict__ x_cat,
    const float* __restrict__ x_num,
    const float* __restrict__ table,
    const float* __restrict__ W_num,
    const float* __restrict__ bias,
    float* __restrict__ out,
    int nrows)
{
    __shared__ float tab[SROWS * SSTR];   // 68,960 B -> 2 blocks/CU
    __shared__ float wsum[24];            // padded; wsum[23] = 0

    const int tid = threadIdx.x;
    const int rl  = tid >> 2;   // local row within pass
    const int g   = tid & 3;    // dim-group: dims [4g, 4g+4)
    const int wb  = 6 * g;

    const int row0 = blockIdx.x * RPB + rl;    // grid*RPB == nrows, no guards
    const int row1 = row0 + RPP;

    // ================= PROLOGUE: issue everything high-latency =================
    // Both passes' x_cat, lane-split (ints [4g,4g+4)) + all-lane int16.
    const int* xc0 = x_cat + (size_t)row0 * NF;
    const int4u av = *(const int4u*)(xc0 + g * 4);
    const int  a16 = xc0[16];
    const int* xc1 = x_cat + (size_t)row1 * NF;
    const int4u cv = *(const int4u*)(xc1 + g * 4);
    const int  c16 = xc1[16];

    // Swizzle the 6 gather indices (LDS pipe — fine pre-barrier), then issue
    // all 6 big-field gathers; staging + barrier covers their latency.
    const int bc4  = SWZ(av.x, 1);   // f4  (k=4:  slot x, lane 1)
    const int bc10 = SWZ(av.z, 2);   // f10 (k=10: slot z, lane 2)
    const int bc14 = SWZ(av.z, 3);   // f14 (k=14: slot z, lane 3)
    const int dc4  = SWZ(cv.x, 1);
    const int dc10 = SWZ(cv.z, 2);
    const int dc14 = SWZ(cv.z, 3);
    const float4 gv00 = *(const float4*)(table + (size_t)(bc4  +     653) * ED + g * 4);
    const float4 gv01 = *(const float4*)(table + (size_t)(bc10 + 1000787) * ED + g * 4);
    const float4 gv02 = *(const float4*)(table + (size_t)(bc14 + 1001846) * ED + g * 4);
    const float4 gv10 = *(const float4*)(table + (size_t)(dc4  +     653) * ED + g * 4);
    const float4 gv11 = *(const float4*)(table + (size_t)(dc10 + 1000787) * ED + g * 4);
    const float4 gv12 = *(const float4*)(table + (size_t)(dc14 + 1001846) * ED + g * 4);

    // pass-0 numeric slice
    const float* xp0 = x_num + (size_t)row0 * NN;
    const float4u xa0 = *(const float4u*)(xp0 + wb);
    float xb0_0, xb1_0;
    if (g < 3) { const float2u t = *(const float2u*)(xp0 + wb + 4); xb0_0 = t.x; xb1_0 = t.y; }
    else       { xb0_0 = xp0[22]; xb1_0 = 0.f; }

    if (tid < 24) {
        float a = 0.f;
        if (tid < NN) {
            #pragma unroll
            for (int d = 0; d < ED; ++d) a += W_num[d * NN + tid];
        }
        wsum[tid] = a;
    }

    // ---- Staging: hand-unrolled 4 independent clamped iterations (the
    // variable-trip-count loop serialized its L2 loads). i3 clamps to the last
    // element; duplicate writes of the same value are benign.
    {
        const int i0 = tid, i1 = tid + BLK, i2 = tid + 2 * BLK;
        int i3 = tid + 3 * BLK; if (i3 > SROWS * 4 - 1) i3 = SROWS * 4 - 1;
        const int r0 = i0 >> 2, q0 = i0 & 3;
        const int r1 = i1 >> 2, q1 = i1 & 3;
        const int r2 = i2 >> 2, q2 = i2 & 3;
        const int r3 = i3 >> 2, q3 = i3 & 3;
        const int d0 = (r0 < 653) ? 0 : (r0 < 787) ? 1000000 : (r0 < 845) ? 1001001 : 1003001;
        const int d1 = (r1 < 653) ? 0 : (r1 < 787) ? 1000000 : (r1 < 845) ? 1001001 : 1003001;
        const int d2 = (r2 < 653) ? 0 : (r2 < 787) ? 1000000 : (r2 < 845) ? 1001001 : 1003001;
        const int d3 = (r3 < 653) ? 0 : (r3 < 787) ? 1000000 : (r3 < 845) ? 1001001 : 1003001;
        const float4 v0 = *(const float4*)(table + (size_t)(r0 + d0) * ED + q0 * 4);
        const float4 v1 = *(const float4*)(table + (size_t)(r1 + d1) * ED + q1 * 4);
        const float4 v2 = *(const float4*)(table + (size_t)(r2 + d2) * ED + q2 * 4);
        const float4 v3 = *(const float4*)(table + (size_t)(r3 + d3) * ED + q3 * 4);
        *(float4*)&tab[r0 * SSTR + q0 * 4] = v0;
        *(float4*)&tab[r1 * SSTR + q1 * 4] = v1;
        *(float4*)&tab[r2 * SSTR + q2 * 4] = v2;
        *(float4*)&tab[r3 * SSTR + q3 * 4] = v3;
    }
    __syncthreads();

    const float b0 = bias[0];
    const float2v wp0 = {wsum[wb],     wsum[wb + 1]};
    const float2v wp1 = {wsum[wb + 2], wsum[wb + 3]};
    const float2v wp2 = {wsum[wb + 4], wsum[wb + 5]};

    // ---- Pass 0 math ----
    {
        float2v lv = {0.f, 0.f};
        lv += float2v{xa0.x, xa0.y} * wp0;
        lv += float2v{xa0.z, xa0.w} * wp1;
        lv += float2v{xb0_0, xb1_0} * wp2;

        int pr[14];
        pr[0]  = SWZ(av.x, 0);         pr[1]  = 500 + SWZ(av.y, 0);
        pr[2]  = 550 + SWZ(av.z, 0);   pr[3]  = 650 + SWZ(av.w, 0);
        pr[4]  = 653 + SWZ(av.y, 1);   pr[5]  = 663 + SWZ(av.z, 1);
        pr[6]  = 683 + SWZ(av.w, 1);   pr[7]  = 783 + SWZ(av.x, 2);
        pr[8]  = 785 + SWZ(av.y, 2);   pr[9]  = 787 + SWZ(av.w, 2);
        pr[10] = 791 + SWZ(av.x, 3);   pr[11] = 795 + SWZ(av.y, 3);
        pr[12] = 845 + SWZ(av.w, 3);   pr[13] = 855 + a16;

        float2v sa = {0.f, 0.f}, sb = {0.f, 0.f}, sq2 = {0.f, 0.f};
        #pragma unroll
        for (int k = 0; k < 14; ++k)
            acc4(*(const float4*)&tab[pr[k] * SSTR + g * 4], sa, sb, sq2);

        acc4(gv00, sa, sb, sq2);
        acc4(gv01, sa, sb, sq2);
        acc4(gv02, sa, sb, sq2);

        const float s0 = sa.x, s1 = sa.y, s2 = sb.x, s3 = sb.y;
        const float sq = sq2.x + sq2.y;
        float contrib = (s0 + s1 + s2 + s3) + (lv.x + lv.y)
                      + 0.5f * ((s0 * s0 + s1 * s1 + s2 * s2 + s3 * s3) - sq);
        contrib += __shfl_xor(contrib, 1);
        contrib += __shfl_xor(contrib, 2);
        if (g == 0) out[row0] = b0 + contrib;
    }

    // ---- Pass-1 x_num (latency hidden under pass-1 swizzles/addr work) ----
    const float* xp1 = x_num + (size_t)row1 * NN;
    const float4u xa1 = *(const float4u*)(xp1 + wb);
    float xb0_1, xb1_1;
    if (g < 3) { const float2u t = *(const float2u*)(xp1 + wb + 4); xb0_1 = t.x; xb1_1 = t.y; }
    else       { xb0_1 = xp1[22]; xb1_1 = 0.f; }

    // ---- Pass 1 math (gathers already resident) ----
    {
        int pr[14];
        pr[0]  = SWZ(cv.x, 0);         pr[1]  = 500 + SWZ(cv.y, 0);
        pr[2]  = 550 + SWZ(cv.z, 0);   pr[3]  = 650 + SWZ(cv.w, 0);
        pr[4]  = 653 + SWZ(cv.y, 1);   pr[5]  = 663 + SWZ(cv.z, 1);
        pr[6]  = 683 + SWZ(cv.w, 1);   pr[7]  = 783 + SWZ(cv.x, 2);
        pr[8]  = 785 + SWZ(cv.y, 2);   pr[9]  = 787 + SWZ(cv.w, 2);
        pr[10] = 791 + SWZ(cv.x, 3);   pr[11] = 795 + SWZ(cv.y, 3);
        pr[12] = 845 + SWZ(cv.w, 3);   pr[13] = 855 + c16;

        float2v lv = {0.f, 0.f};
        lv += float2v{xa1.x, xa1.y} * wp0;
        lv += float2v{xa1.z, xa1.w} * wp1;
        lv += float2v{xb0_1, xb1_1} * wp2;

        float2v sa = {0.f, 0.f}, sb = {0.f, 0.f}, sq2 = {0.f, 0.f};
        #pragma unroll
        for (int k = 0; k < 14; ++k)
            acc4(*(const float4*)&tab[pr[k] * SSTR + g * 4], sa, sb, sq2);

        acc4(gv10, sa, sb, sq2);
        acc4(gv11, sa, sb, sq2);
        acc4(gv12, sa, sb, sq2);

        const float s0 = sa.x, s1 = sa.y, s2 = sb.x, s3 = sb.y;
        const float sq = sq2.x + sq2.y;
        float contrib = (s0 + s1 + s2 + s3) + (lv.x + lv.y)
                      + 0.5f * ((s0 * s0 + s1 * s1 + s2 * s2 + s3 * s3) - sq);
        contrib += __shfl_xor(contrib, 1);
        contrib += __shfl_xor(contrib, 2);
        if (g == 0) out[row1] = b0 + contrib;
    }
}

extern "C" void kernel_launch(void* const* d_in, const int* in_sizes, int n_in,
                              void* d_out, int out_size, void* d_ws, size_t ws_size,
                              hipStream_t stream) {
    const int*   x_cat = (const int*)  d_in[0];
    const float* x_num = (const float*)d_in[1];
    const float* table = (const float*)d_in[2];
    const float* W_num = (const float*)d_in[3];
    const float* bias  = (const float*)d_in[4];
    float* out = (float*)d_out;

    const int nrows = out_size;                 // 262144
    const int grid = (nrows + RPB - 1) / RPB;   // 512
    ffm_fwd_kernel<<<grid, BLK, 0, stream>>>(x_cat, x_num, table, W_num, bias, out, nrows);
}

// Round 13
// 18.474 us; speedup vs baseline: 1.3948x; 1.3948x over previous
//
#include <hip/hip_runtime.h>

#define NF 17
#define NN 23
#define ED 16
#define BLK 512      // 8 waves/block -> 4 co-resident blocks/CU (32 waves)
#define RPP 128      // rows per pass = BLK/4
#define RPB 256      // rows per block (2 passes); grid*RPB == nrows exactly
#define SROWS 362    // packed rows of the 13 small-vocab fields (f0 evicted)
#define SSTR 20      // padded floats per LDS row (80 B)

typedef int   int4u    __attribute__((ext_vector_type(4), aligned(4)));
typedef float float4u  __attribute__((ext_vector_type(4), aligned(4)));
typedef float float2u  __attribute__((ext_vector_type(2), aligned(4)));
typedef float float2v  __attribute__((ext_vector_type(2)));

// packed accumulate: 2x v_pk_add_f32 + 2x v_pk_fma_f32 per field
__device__ __forceinline__ void acc4(const float4 v, float2v& sa, float2v& sb,
                                     float2v& sq2) {
    const float2v lo = {v.x, v.y};
    const float2v hi = {v.z, v.w};
    sa += lo;
    sb += hi;
    sq2 += lo * lo;
    sq2 += hi * hi;
}

__global__ __launch_bounds__(BLK, 8) void ffm_fwd_kernel(
    const int* __restrict__ x_cat,
    const float* __restrict__ x_num,
    const float* __restrict__ table,
    const float* __restrict__ W_num,
    const float* __restrict__ bias,
    float* __restrict__ out,
    int nrows)
{
    __shared__ float tab[SROWS * SSTR];   // 28,960 B -> 4 blocks/CU
    __shared__ float wsum[24];            // padded; wsum[23] = 0

    const int tid = threadIdx.x;
    const int rl  = tid >> 2;   // local row within pass (0..127)
    const int g   = tid & 3;    // dim-group: dims [4g, 4g+4)
    const int wb  = 6 * g;

    const int row0 = blockIdx.x * RPB + rl;    // grid*RPB == nrows, no guards
    const int row1 = row0 + RPP;

    // ---- Pass-0 prefetch BEFORE staging: x_cat, then its 4 gathers ----
    const int* xc0 = x_cat + (size_t)row0 * NF;
    const int4u a0 = *(const int4u*)(xc0);
    const int4u a1 = *(const int4u*)(xc0 + 4);
    const int4u a2 = *(const int4u*)(xc0 + 8);
    const int4u a3 = *(const int4u*)(xc0 + 12);
    const int  a16 = xc0[16];
    // gathers: f0 (L2-hot 32KB slice), f4 (1M), f10 (1001), f14 (2000)
    const float4 gv00 = *(const float4*)(table + (size_t)(a0.x          ) * ED + g * 4);
    const float4 gv01 = *(const float4*)(table + (size_t)(a1.x +     653) * ED + g * 4);
    const float4 gv02 = *(const float4*)(table + (size_t)(a2.z + 1000787) * ED + g * 4);
    const float4 gv03 = *(const float4*)(table + (size_t)(a3.z + 1001846) * ED + g * 4);

    const float* xp0 = x_num + (size_t)row0 * NN;
    const float4u xa0 = *(const float4u*)(xp0 + wb);
    float xb0_0, xb1_0;
    if (g < 3) { const float2u t = *(const float2u*)(xp0 + wb + 4); xb0_0 = t.x; xb1_0 = t.y; }
    else       { xb0_0 = xp0[22]; xb1_0 = 0.f; }

    if (tid < 24) {
        float a = 0.f;
        if (tid < NN) {
            #pragma unroll
            for (int d = 0; d < ED; ++d) a += W_num[d * NN + tid];
        }
        wsum[tid] = a;
    }

    // ---- Stage the 13 small-vocab fields (362 rows, 29 KB) once per block ----
    // packed row r -> global table row r + d:
    //   [0,153):   +500      (f1,f2,f3)
    //   [153,287): +1000500  (f5,f6,f7,f8,f9)
    //   [287,345): +1001501  (f11,f12,f13)
    //   [345,362): +1003501  (f15,f16)
    for (int i = tid; i < SROWS * 4; i += BLK) {
        const int r = i >> 2, q = i & 3;
        const int d = (r < 153) ? 500 : (r < 287) ? 1000500 : (r < 345) ? 1001501 : 1003501;
        *(float4*)&tab[r * SSTR + q * 4] =
            *(const float4*)(table + (size_t)(r + d) * ED + q * 4);
    }
    __syncthreads();

    const float b0 = bias[0];
    const float2v wp0 = {wsum[wb],     wsum[wb + 1]};
    const float2v wp1 = {wsum[wb + 2], wsum[wb + 3]};
    const float2v wp2 = {wsum[wb + 4], wsum[wb + 5]};

    // ---- Prefetch pass-1 indices ----
    const int* xc1 = x_cat + (size_t)row1 * NF;
    const int4u c0 = *(const int4u*)(xc1);
    const int4u c1 = *(const int4u*)(xc1 + 4);
    const int4u c2 = *(const int4u*)(xc1 + 8);
    const int4u c3 = *(const int4u*)(xc1 + 12);
    const int  c16 = xc1[16];

    // ---- Pass 0 math ----
    {
        float2v lv = {0.f, 0.f};
        lv += float2v{xa0.x, xa0.y} * wp0;
        lv += float2v{xa0.z, xa0.w} * wp1;
        lv += float2v{xb0_0, xb1_0} * wp2;

        int pr[13];
        pr[0]  = a0.y;        pr[1]  = 50 + a0.z;   pr[2]  = 150 + a0.w;
        pr[3]  = 153 + a1.y;  pr[4]  = 163 + a1.z;  pr[5]  = 183 + a1.w;
        pr[6]  = 283 + a2.x;  pr[7]  = 285 + a2.y;  pr[8]  = 287 + a2.w;
        pr[9]  = 291 + a3.x;  pr[10] = 295 + a3.y;  pr[11] = 345 + a3.w;
        pr[12] = 355 + a16;

        float2v sa = {0.f, 0.f}, sb = {0.f, 0.f}, sq2 = {0.f, 0.f};
        #pragma unroll
        for (int k = 0; k < 13; ++k)
            acc4(*(const float4*)&tab[pr[k] * SSTR + g * 4], sa, sb, sq2);

        acc4(gv00, sa, sb, sq2);
        acc4(gv01, sa, sb, sq2);
        acc4(gv02, sa, sb, sq2);
        acc4(gv03, sa, sb, sq2);

        const float s0 = sa.x, s1 = sa.y, s2 = sb.x, s3 = sb.y;
        const float sq = sq2.x + sq2.y;
        float contrib = (s0 + s1 + s2 + s3) + (lv.x + lv.y)
                      + 0.5f * ((s0 * s0 + s1 * s1 + s2 * s2 + s3 * s3) - sq);
        contrib += __shfl_xor(contrib, 1);
        contrib += __shfl_xor(contrib, 2);
        if (g == 0) out[row0] = b0 + contrib;
    }

    // ---- Pass-1 gathers (indices already resident) + x_num ----
    const float4 gv10 = *(const float4*)(table + (size_t)(c0.x          ) * ED + g * 4);
    const float4 gv11 = *(const float4*)(table + (size_t)(c1.x +     653) * ED + g * 4);
    const float4 gv12 = *(const float4*)(table + (size_t)(c2.z + 1000787) * ED + g * 4);
    const float4 gv13 = *(const float4*)(table + (size_t)(c3.z + 1001846) * ED + g * 4);

    const float* xp1 = x_num + (size_t)row1 * NN;
    const float4u xa1 = *(const float4u*)(xp1 + wb);
    float xb0_1, xb1_1;
    if (g < 3) { const float2u t = *(const float2u*)(xp1 + wb + 4); xb0_1 = t.x; xb1_1 = t.y; }
    else       { xb0_1 = xp1[22]; xb1_1 = 0.f; }

    // ---- Pass 1 math ----
    {
        float2v lv = {0.f, 0.f};
        lv += float2v{xa1.x, xa1.y} * wp0;
        lv += float2v{xa1.z, xa1.w} * wp1;
        lv += float2v{xb0_1, xb1_1} * wp2;

        int pr[13];
        pr[0]  = c0.y;        pr[1]  = 50 + c0.z;   pr[2]  = 150 + c0.w;
        pr[3]  = 153 + c1.y;  pr[4]  = 163 + c1.z;  pr[5]  = 183 + c1.w;
        pr[6]  = 283 + c2.x;  pr[7]  = 285 + c2.y;  pr[8]  = 287 + c2.w;
        pr[9]  = 291 + c3.x;  pr[10] = 295 + c3.y;  pr[11] = 345 + c3.w;
        pr[12] = 355 + c16;

        float2v sa = {0.f, 0.f}, sb = {0.f, 0.f}, sq2 = {0.f, 0.f};
        #pragma unroll
        for (int k = 0; k < 13; ++k)
            acc4(*(const float4*)&tab[pr[k] * SSTR + g * 4], sa, sb, sq2);

        acc4(gv10, sa, sb, sq2);
        acc4(gv11, sa, sb, sq2);
        acc4(gv12, sa, sb, sq2);
        acc4(gv13, sa, sb, sq2);

        const float s0 = sa.x, s1 = sa.y, s2 = sb.x, s3 = sb.y;
        const float sq = sq2.x + sq2.y;
        float contrib = (s0 + s1 + s2 + s3) + (lv.x + lv.y)
                      + 0.5f * ((s0 * s0 + s1 * s1 + s2 * s2 + s3 * s3) - sq);
        contrib += __shfl_xor(contrib, 1);
        contrib += __shfl_xor(contrib, 2);
        if (g == 0) out[row1] = b0 + contrib;
    }
}

extern "C" void kernel_launch(void* const* d_in, const int* in_sizes, int n_in,
                              void* d_out, int out_size, void* d_ws, size_t ws_size,
                              hipStream_t stream) {
    const int*   x_cat = (const int*)  d_in[0];
    const float* x_num = (const float*)d_in[1];
    const float* table = (const float*)d_in[2];
    const float* W_num = (const float*)d_in[3];
    const float* bias  = (const float*)d_in[4];
    float* out = (float*)d_out;

    const int nrows = out_size;                 // 262144
    const int grid = (nrows + RPB - 1) / RPB;   // 1024
    ffm_fwd_kernel<<<grid, BLK, 0, stream>>>(x_cat, x_num, table, W_num, bias, out, nrows);
}